// Round 9
// baseline (173.491 us; speedup 1.0000x reference)
//
#include <hip/hip_runtime.h>
#include <hip/hip_bf16.h>

typedef __bf16 bf16x8 __attribute__((ext_vector_type(8)));
typedef float f32x4 __attribute__((ext_vector_type(4)));
typedef unsigned short u16;
typedef u16 u16x8 __attribute__((ext_vector_type(8)));
typedef unsigned int u32;
typedef u32 u32x4 __attribute__((ext_vector_type(4)));

#define N_EMBD 1024
#define NH 16
#define HD 64
#define BZ 4
#define TZ 2048
#define QSCALE 0.18033688011f   // 1/sqrt(64) * log2(e)

template<bool B> struct BoolC { static constexpr bool value = B; };

__device__ __forceinline__ u16 f2bf(float f) {
    return __builtin_bit_cast(u16, (__bf16)f);
}

__device__ __forceinline__ void gload16(const void* g, void* l) {
    __builtin_amdgcn_global_load_lds(
        (const __attribute__((address_space(1))) void*)g,
        (__attribute__((address_space(3))) void*)l, 16, 0, 0);
}

// ---------------- fused fp32 -> bf16 converts (x + 4 weights) --------------
__global__ void cvt_all(const float* __restrict__ x,  const float* __restrict__ Wq,
                        const float* __restrict__ Wk, const float* __restrict__ Wv,
                        const float* __restrict__ Wc, u16* __restrict__ xb,
                        u16* __restrict__ wqkv, u16* __restrict__ wcb) {
    const int blk = blockIdx.x;
    const float* src; u16* dst; int base; float scale = 1.0f;
    if (blk < 8192)       { src = x;  dst = xb;             base = blk; }
    else if (blk < 9216)  { src = Wq; dst = wqkv;           base = blk - 8192; scale = QSCALE; }
    else if (blk < 10240) { src = Wk; dst = wqkv + 1048576; base = blk - 9216; }
    else if (blk < 11264) { src = Wv; dst = wqkv + 2097152; base = blk - 10240; }
    else                  { src = Wc; dst = wcb;            base = blk - 11264; }
    const int i = base * 256 + threadIdx.x;
    float4 f = ((const float4*)src)[i];
    ushort4 o;
    o.x = f2bf(f.x * scale); o.y = f2bf(f.y * scale);
    o.z = f2bf(f.z * scale); o.w = f2bf(f.w * scale);
    ((ushort4*)dst)[i] = o;
}

// ---------------- bf16 GEMM, C = A * B^T + bias (256x128) ------------------
// Round-2 verified kernel: 6-region rotating LDS pipeline (144 KiB), one
// barrier per 32-wide K phase, counted vmcnt(9), 88 VGPR, 2 blocks/CU.
template<int EPI>
__global__ __launch_bounds__(512, 2) void gemm_bt(
    const u16* __restrict__ A, const u16* __restrict__ Bm,
    const float* __restrict__ b0, const float* __restrict__ b1, const float* __restrict__ b2,
    void* __restrict__ Cout, int K) {
    __shared__ __align__(16) u16 Ash[6 * 8192];   // 6 x (256 rows x 32 k) = 96 KB
    __shared__ __align__(16) u16 Bsh[6 * 4096];   // 6 x (128 rows x 32 k) = 48 KB

    const int tid = threadIdx.x;
    const int lane = tid & 63, wid = tid >> 6;
    const int wm = wid >> 1, wn = wid & 1;        // 4M x 2N wave grid
    const int m0 = blockIdx.x * 256, n0 = blockIdx.y * 128;
    const int r = lane & 15, g = lane >> 4;

    f32x4 acc[4][4] = {};

    const int p0 = tid >> 3;
    const int ci = tid & 7;
    const int cl = ci ^ (p0 & 7);
    const int trow = 2 * p0 + (cl >> 2);
    const int colb = (cl & 3) * 8;
    const u16* aS = A + (long)(m0 + trow) * K + colb;
    const u16* bS = Bm + (long)(n0 + trow) * K + colb;
    const long rowskip = (long)128 * K;
    const int ldst = tid * 8;

    auto STAGE = [&](int sig, int kq) {
        const u16* spA = aS + kq * 32;
        gload16(spA, &Ash[sig * 8192 + ldst]);
        gload16(spA + rowskip, &Ash[sig * 8192 + 4096 + ldst]);
        gload16(bS + kq * 32, &Bsh[sig * 4096 + ldst]);
    };

    const int xa = (((((r & 1) << 2) | g) ^ (r >> 1)) << 4);
    const int arow0 = wm * 32 + (r >> 1);
    const int brow0 = wn * 32 + (r >> 1);
    auto RD = [&](const u16* base, int prow) -> bf16x8 {
        return *(const bf16x8*)((const char*)base + prow * 128 + xa);
    };

    bf16x8 fa0[4], fb0[4], fa1[4], fb1[4];

    auto READF = [&](int rho, bf16x8* fa, bf16x8* fb) {
#pragma unroll
        for (int m = 0; m < 4; ++m) fa[m] = RD(&Ash[rho * 8192], arow0 + m * 8);
#pragma unroll
        for (int n = 0; n < 4; ++n) fb[n] = RD(&Bsh[rho * 4096], brow0 + n * 8);
    };
    auto MM = [&](bf16x8* fa, bf16x8* fb) {
        __builtin_amdgcn_s_setprio(1);
#pragma unroll
        for (int m = 0; m < 4; ++m)
#pragma unroll
            for (int n = 0; n < 4; ++n)
                acc[m][n] = __builtin_amdgcn_mfma_f32_16x16x32_bf16(fa[m], fb[n], acc[m][n], 0, 0, 0);
        __builtin_amdgcn_s_setprio(0);
    };
    auto BAR = [&] {
        asm volatile("" ::: "memory");
        __builtin_amdgcn_s_barrier();
        asm volatile("" ::: "memory");
    };

    const int nph = K >> 5;

    STAGE(0, 0); STAGE(1, 1); STAGE(2, 2); STAGE(3, 3); STAGE(4, 4);
    asm volatile("s_waitcnt vmcnt(9)" ::: "memory");
    BAR();
    READF(0, fa0, fb0);

    int rho = 0;
    for (int p = 0; p + 2 < nph; p += 2) {
        const int rho1 = rho + 1;
        const int rho2 = (rho + 2 == 6) ? 0 : rho + 2;
        const int sigE = (rho == 0) ? 5 : rho - 1;
        const int kqE = (p + 5 < nph) ? p + 5 : 0;
        const int kqO = (p + 6 < nph) ? p + 6 : 0;
        BAR();
        READF(rho1, fa1, fb1);
        STAGE(sigE, kqE);
        MM(fa0, fb0);
        asm volatile("s_waitcnt vmcnt(9)" ::: "memory");
        BAR();
        READF(rho2, fa0, fb0);
        STAGE(rho, kqO);
        MM(fa1, fb1);
        asm volatile("s_waitcnt vmcnt(9)" ::: "memory");
        rho = rho2;
    }
    {
        const int rho1 = rho + 1;
        const int sigE = (rho == 0) ? 5 : rho - 1;
        BAR();
        READF(rho1, fa1, fb1);
        STAGE(sigE, 0);
        MM(fa0, fb0);
        asm volatile("s_waitcnt vmcnt(9)" ::: "memory");
    }
    MM(fa1, fb1);
    asm volatile("s_waitcnt vmcnt(0)" ::: "memory");

    const long planeSz = (long)BZ * NH * TZ * HD;
    if constexpr (EPI == 0) {
        const int proj = n0 >> 10;
        u16* outp = (u16*)Cout;
        if (proj == 2) {
            const int bi = (m0 + wm * 64) >> 11;
#pragma unroll
            for (int n = 0; n < 4; ++n) {
                const int rr = (n0 & 1023) + wn * 64 + n * 16 + r;
                const int h = rr >> 6, d = rr & 63;
                const float bias = b2[rr];
                u16* vcol = outp + 2 * planeSz + (((long)bi * NH + h) * HD + d) * TZ;
#pragma unroll
                for (int m = 0; m < 4; ++m) {
                    const int t0 = (m0 + wm * 64 + m * 16 + g * 4) & 2047;
                    ushort4 o;
                    o.x = f2bf(acc[m][n][0] + bias);
                    o.y = f2bf(acc[m][n][1] + bias);
                    o.z = f2bf(acc[m][n][2] + bias);
                    o.w = f2bf(acc[m][n][3] + bias);
                    *(ushort4*)(vcol + t0) = o;
                }
            }
        } else {
#pragma unroll
            for (int n = 0; n < 4; ++n) {
                const int rr = (n0 & 1023) + wn * 64 + n * 16 + r;
                const int h = rr >> 6, d = rr & 63;
                float bias = (proj == 0 ? b0 : b1)[rr];
                if (proj == 0) bias *= QSCALE;
                const long pbase = (long)proj * planeSz + d;
#pragma unroll
                for (int m = 0; m < 4; ++m)
#pragma unroll
                    for (int reg = 0; reg < 4; ++reg) {
                        const int row = m0 + wm * 64 + m * 16 + g * 4 + reg;
                        const int bi = row >> 11, t = row & 2047;
                        outp[pbase + ((long)bi * NH + h) * (TZ * HD) + (long)t * HD] =
                            f2bf(acc[m][n][reg] + bias);
                    }
            }
        }
    } else {
        float* outp = (float*)Cout;
#pragma unroll
        for (int n = 0; n < 4; ++n) {
            const int col = n0 + wn * 64 + n * 16 + r;
            const float bias = b0[col];
#pragma unroll
            for (int m = 0; m < 4; ++m)
#pragma unroll
                for (int reg = 0; reg < 4; ++reg) {
                    const int row = m0 + wm * 64 + m * 16 + g * 4 + reg;
                    outp[(long)row * N_EMBD + col] = acc[m][n][reg] + bias;
                }
        }
    }
}

// ---------------- flash attention (causal, swapped-operand, in-register P) ----
// grid: 512 blocks, 512 threads = 8 waves; wave owns 16 q-rows; KVBLK = 128.
// Attention is VALU-issue-bound (r6: VALUBusy 59%, MfmaUtil 20%); ~60% of VALU
// is PER-TILE fixed overhead. KVBLK 64->128 halves tile count -> fixed costs.
// LDS: K[128][64] + V^T[64][128] double-buffered = 64 KiB -> 2 blocks/CU.
// Block = BALANCED PAIR of 128-row q-blocks: (15-pr, pr) -> 17 k-tiles of 128.
// Only the final (diagonal) tile needs masking.
__device__ __forceinline__ bf16x8 lds_swz8(const u16* base, int row, int colByte) {
    return *(const bf16x8*)((const char*)base + row * 128 + (colByte ^ ((row & 7) << 4)));
}
__device__ __forceinline__ bf16x8 lds_swzV(const u16* base, int row, int colByte) {
    // 256B row stride (row = d, 128 k-cols); XOR spreads 8 chunk slots -> 2-way
    return *(const bf16x8*)((const char*)base + row * 256 + (colByte ^ ((row & 7) << 4)));
}

__global__ __launch_bounds__(512, 2) void attn_fwd(const u16* __restrict__ qkv, u16* __restrict__ yb) {
    const int i = blockIdx.x;
    const int xcd = i & 7, slot = i >> 3;
    const int bh = xcd + 8 * (slot & 7);     // 0..63, same-bh blocks share an XCD
    const int pr = slot >> 3;                // 0..7 pair id
    const int b = bh >> 4, h = bh & 15;
    const int tid = threadIdx.x, lane = tid & 63, w = tid >> 6;   // w 0..7
    const int r = lane & 15, g = lane >> 4;

    __shared__ __align__(16) u16 Ksh[2][128 * 64];   // [k][d] swizzled, 16KB/buf
    __shared__ __align__(16) u16 Vsh[2][64 * 128];   // [d][k] swizzled, 16KB/buf

    const long planeSz = (long)BZ * NH * TZ * HD;
    const long bhoff = ((long)b * NH + h) * (long)TZ * HD;
    const u16* qp = qkv + bhoff;
    const u16* kp = qkv + planeSz + bhoff;
    const u16* vTp = qkv + 2 * planeSz + bhoff;      // [64][T]

    // staging coords (512 threads): K rows via tid>>3 (2 rounds: +0, +64);
    // V rows via tid>>4 (2 rounds: +0, +32). Row offsets are %8==0 so the
    // XOR source swizzle is identical across rounds.
    const int rr8 = tid >> 3;
    const int ssk = ((tid & 7) ^ (rr8 & 7)) * 8;
    const int vrow = tid >> 4;
    const int ssv = ((tid & 15) ^ (vrow & 7)) * 8;

    auto STAGE = [&](int buf, int k0) {
        gload16(kp + (long)(k0 + rr8) * HD + ssk, &Ksh[buf][tid * 8]);
        gload16(kp + (long)(k0 + 64 + rr8) * HD + ssk, &Ksh[buf][4096 + tid * 8]);
        gload16(vTp + (long)vrow * TZ + k0 + ssv, &Vsh[buf][tid * 8]);
        gload16(vTp + (long)(32 + vrow) * TZ + k0 + ssv, &Vsh[buf][4096 + tid * 8]);
    };

#pragma unroll 1
    for (int it = 0; it < 2; ++it) {
        const int qblk = it ? pr : (15 - pr);
        const int q0 = qblk * 128;
        const int nkt = qblk + 1;              // 128-wide k tiles
        const int q = q0 + w * 16 + r;

        // hoist Q fragments (B-operand: lane r = q-col, g*8 = d-chunk)
        bf16x8 qf[2];
#pragma unroll
        for (int ks = 0; ks < 2; ++ks)
            qf[ks] = *(const bf16x8*)(qp + (long)q * HD + ks * 32 + g * 8);

        f32x4 yacc[4] = {};                    // y^T: [d-frag][q=r]
        float mrun = -__builtin_inff(), lpart = 0.f;

        STAGE(0, 0);                           // prologue stage tile 0

        auto tile = [&](int kt, auto maskc) {
            constexpr bool MASK = decltype(maskc)::value;
            const int cur = kt & 1;
            const int k0 = kt * 128;
            if (kt + 1 < nkt) {
                STAGE(cur ^ 1, k0 + 128);
                asm volatile("s_waitcnt vmcnt(4)" ::: "memory");
            } else {
                asm volatile("s_waitcnt vmcnt(0)" ::: "memory");
            }
            __builtin_amdgcn_s_barrier();
            asm volatile("" ::: "memory");

            // S^T = K · Q^T  -> sac[nk]: row k (nk*16+g*4+reg), col q (r)
            f32x4 sac[8] = {};
#pragma unroll
            for (int ks = 0; ks < 2; ++ks) {
                bf16x8 kf[8];
#pragma unroll
                for (int nk = 0; nk < 8; ++nk)
                    kf[nk] = lds_swz8(Ksh[cur], nk * 16 + r, ks * 64 + g * 16);
                __builtin_amdgcn_s_setprio(1);
#pragma unroll
                for (int nk = 0; nk < 8; ++nk)
                    sac[nk] = __builtin_amdgcn_mfma_f32_16x16x32_bf16(kf[nk], qf[ks], sac[nk], 0, 0, 0);
                __builtin_amdgcn_s_setprio(0);
            }

            if constexpr (MASK) {
#pragma unroll
                for (int nk = 0; nk < 8; ++nk)
#pragma unroll
                    for (int reg = 0; reg < 4; ++reg) {
                        const int k = k0 + nk * 16 + g * 4 + reg;
                        sac[nk][reg] = (k > q) ? -__builtin_inff() : sac[nk][reg];
                    }
            }

            // online softmax (log2 domain). lane owns 32 k of q-row r.
            float pmax;
            {
                float t0 = fmaxf(fmaxf(sac[0][0], sac[0][1]), fmaxf(sac[0][2], sac[0][3]));
                float t1 = fmaxf(fmaxf(sac[1][0], sac[1][1]), fmaxf(sac[1][2], sac[1][3]));
                float t2 = fmaxf(fmaxf(sac[2][0], sac[2][1]), fmaxf(sac[2][2], sac[2][3]));
                float t3 = fmaxf(fmaxf(sac[3][0], sac[3][1]), fmaxf(sac[3][2], sac[3][3]));
                float t4 = fmaxf(fmaxf(sac[4][0], sac[4][1]), fmaxf(sac[4][2], sac[4][3]));
                float t5 = fmaxf(fmaxf(sac[5][0], sac[5][1]), fmaxf(sac[5][2], sac[5][3]));
                float t6 = fmaxf(fmaxf(sac[6][0], sac[6][1]), fmaxf(sac[6][2], sac[6][3]));
                float t7 = fmaxf(fmaxf(sac[7][0], sac[7][1]), fmaxf(sac[7][2], sac[7][3]));
                pmax = fmaxf(fmaxf(fmaxf(t0, t1), fmaxf(t2, t3)),
                             fmaxf(fmaxf(t4, t5), fmaxf(t6, t7)));
            }
            if (__any(pmax > mrun + 8.0f)) {
                float mx = pmax;
                mx = fmaxf(mx, __shfl_xor(mx, 16));
                mx = fmaxf(mx, __shfl_xor(mx, 32));
                const float mnew = fmaxf(mrun, mx);
                const float corr = __builtin_amdgcn_exp2f(mrun - mnew);
                lpart *= corr;
#pragma unroll
                for (int nd = 0; nd < 4; ++nd)
                    yacc[nd] *= corr;
                mrun = mnew;
            }
            float rsum = 0.f;
#pragma unroll
            for (int nk = 0; nk < 8; ++nk) {
                float p0 = __builtin_amdgcn_exp2f(sac[nk][0] - mrun);
                float p1 = __builtin_amdgcn_exp2f(sac[nk][1] - mrun);
                float p2 = __builtin_amdgcn_exp2f(sac[nk][2] - mrun);
                float p3 = __builtin_amdgcn_exp2f(sac[nk][3] - mrun);
                sac[nk][0] = p0; sac[nk][1] = p1;
                sac[nk][2] = p2; sac[nk][3] = p3;
                rsum += (p0 + p1) + (p2 + p3);
            }
            lpart += rsum;

            // pack P to bf16 + permlane exchange -> PV B-operand in-register
            u32 wv[8][2];
#pragma unroll
            for (int nk = 0; nk < 8; ++nk)
#pragma unroll
                for (int j2 = 0; j2 < 2; ++j2)
                    asm("v_cvt_pk_bf16_f32 %0, %1, %2"
                        : "=v"(wv[nk][j2])
                        : "v"(sac[nk][2 * j2]), "v"(sac[nk][2 * j2 + 1]));
            u32 pwa[4][4];
#pragma unroll
            for (int ks = 0; ks < 4; ++ks) {
                u32 a0 = wv[2 * ks][0], c0 = wv[2 * ks + 1][0];
                u32 a1 = wv[2 * ks][1], c1 = wv[2 * ks + 1][1];
                asm("v_permlane32_swap_b32 %0, %1" : "+v"(a0), "+v"(c0));
                asm("v_permlane32_swap_b32 %0, %1" : "+v"(a1), "+v"(c1));
                asm("v_permlane16_swap_b32 %0, %1" : "+v"(a0), "+v"(c0));
                asm("v_permlane16_swap_b32 %0, %1" : "+v"(a1), "+v"(c1));
                pwa[ks][0] = a0; pwa[ks][1] = a1;
                pwa[ks][2] = c0; pwa[ks][3] = c1;
            }

            // y^T += V^T · P^T  (4 k-slots of 32)
#pragma unroll
            for (int ks = 0; ks < 4; ++ks) {
                bf16x8 vf[4];
#pragma unroll
                for (int nd = 0; nd < 4; ++nd)
                    vf[nd] = lds_swzV(Vsh[cur], nd * 16 + r, ks * 64 + g * 16);
                const u32x4 pwv = { pwa[ks][0], pwa[ks][1], pwa[ks][2], pwa[ks][3] };
                const bf16x8 pb = __builtin_bit_cast(bf16x8, pwv);
                __builtin_amdgcn_s_setprio(1);
#pragma unroll
                for (int nd = 0; nd < 4; ++nd)
                    yacc[nd] = __builtin_amdgcn_mfma_f32_16x16x32_bf16(vf[nd], pb, yacc[nd], 0, 0, 0);
                __builtin_amdgcn_s_setprio(0);
            }

            asm volatile("" ::: "memory");
            __builtin_amdgcn_s_barrier();
            asm volatile("" ::: "memory");
        };

        for (int kt = 0; kt < nkt - 1; ++kt) tile(kt, BoolC<false>{});
        tile(nkt - 1, BoolC<true>{});          // single diagonal tile

        // epilogue: reduce l across g-lanes, y = y^T / l
        {
            float l = lpart;
            l += __shfl_xor(l, 16);
            l += __shfl_xor(l, 32);
            const float inv = 1.f / l;
            u16* orow = yb + ((long)b * TZ + q) * N_EMBD + h * HD;
#pragma unroll
            for (int nd = 0; nd < 4; ++nd) {
                ushort4 o;
                o.x = f2bf(yacc[nd][0] * inv);
                o.y = f2bf(yacc[nd][1] * inv);
                o.z = f2bf(yacc[nd][2] * inv);
                o.w = f2bf(yacc[nd][3] * inv);
                *(ushort4*)(orow + nd * 16 + g * 4) = o;
            }
        }
    }
}

extern "C" void kernel_launch(void* const* d_in, const int* in_sizes, int n_in,
                              void* d_out, int out_size, void* d_ws, size_t ws_size,
                              hipStream_t stream) {
    const float* x  = (const float*)d_in[0];
    const float* Wq = (const float*)d_in[1];
    const float* bq = (const float*)d_in[2];
    const float* Wk = (const float*)d_in[3];
    const float* bk = (const float*)d_in[4];
    const float* Wv = (const float*)d_in[5];
    const float* bv = (const float*)d_in[6];
    const float* Wc = (const float*)d_in[7];
    const float* bc = (const float*)d_in[8];

    char* ws = (char*)d_ws;
    u16* xb   = (u16*)(ws);                  // 8192x1024 bf16   (16 MB)
    u16* wqkv = (u16*)(ws + 16777216);       // 3072x1024 bf16   (6 MB)
    u16* wcb  = (u16*)(ws + 23068672);       // 1024x1024 bf16   (2 MB)
    u16* qkv  = (u16*)(ws + 25165824);       // Q,K,[V^T] planes (48 MB)
    u16* yb   = (u16*)(ws + 75497472);       // 8192x1024 bf16   (16 MB)

    // fused converts (Wq pre-scaled by QSCALE so S arrives in log2 domain)
    cvt_all<<<12288, 256, 0, stream>>>(x, Wq, Wk, Wv, Wc, xb, wqkv, wcb);

    // qkv projection: [8192,1024] x [3072,1024]^T -> qkv scatter (V transposed)
    gemm_bt<0><<<dim3(32, 24), 512, 0, stream>>>(xb, wqkv, bq, bk, bv, (void*)qkv, 1024);

    // causal attention (128-row paired q-blocks, 8-wave blocks, KVBLK=128)
    attn_fwd<<<512, 512, 0, stream>>>(qkv, yb);

    // output projection: [8192,1024] x [1024,1024]^T + bc -> fp32 out
    gemm_bt<1><<<dim3(32, 8), 512, 0, stream>>>(yb, wcb, bc, nullptr, nullptr, d_out, 1024);
}

// Round 10
// 161.581 us; speedup vs baseline: 1.0737x; 1.0737x over previous
//
#include <hip/hip_runtime.h>
#include <hip/hip_bf16.h>

typedef __bf16 bf16x8 __attribute__((ext_vector_type(8)));
typedef float f32x4 __attribute__((ext_vector_type(4)));
typedef unsigned short u16;
typedef u16 u16x8 __attribute__((ext_vector_type(8)));
typedef unsigned int u32;
typedef u32 u32x4 __attribute__((ext_vector_type(4)));

#define N_EMBD 1024
#define NH 16
#define HD 64
#define BZ 4
#define TZ 2048
#define QSCALE 0.18033688011f   // 1/sqrt(64) * log2(e)

template<bool B> struct BoolC { static constexpr bool value = B; };

__device__ __forceinline__ u16 f2bf(float f) {
    return __builtin_bit_cast(u16, (__bf16)f);
}

__device__ __forceinline__ void gload16(const void* g, void* l) {
    __builtin_amdgcn_global_load_lds(
        (const __attribute__((address_space(1))) void*)g,
        (__attribute__((address_space(3))) void*)l, 16, 0, 0);
}

// ---------------- fused fp32 -> bf16 converts (x + 4 weights) --------------
__global__ void cvt_all(const float* __restrict__ x,  const float* __restrict__ Wq,
                        const float* __restrict__ Wk, const float* __restrict__ Wv,
                        const float* __restrict__ Wc, u16* __restrict__ xb,
                        u16* __restrict__ wqkv, u16* __restrict__ wcb) {
    const int blk = blockIdx.x;
    const float* src; u16* dst; int base; float scale = 1.0f;
    if (blk < 8192)       { src = x;  dst = xb;             base = blk; }
    else if (blk < 9216)  { src = Wq; dst = wqkv;           base = blk - 8192; scale = QSCALE; }
    else if (blk < 10240) { src = Wk; dst = wqkv + 1048576; base = blk - 9216; }
    else if (blk < 11264) { src = Wv; dst = wqkv + 2097152; base = blk - 10240; }
    else                  { src = Wc; dst = wcb;            base = blk - 11264; }
    const int i = base * 256 + threadIdx.x;
    float4 f = ((const float4*)src)[i];
    ushort4 o;
    o.x = f2bf(f.x * scale); o.y = f2bf(f.y * scale);
    o.z = f2bf(f.z * scale); o.w = f2bf(f.w * scale);
    ((ushort4*)dst)[i] = o;
}

// ---------------- bf16 GEMM, C = A * B^T + bias (256x128) ------------------
// Round-2 verified kernel: 6-region rotating LDS pipeline (144 KiB), one
// barrier per 32-wide K phase, counted vmcnt(9), 88 VGPR, 2 blocks/CU.
template<int EPI>
__global__ __launch_bounds__(512, 2) void gemm_bt(
    const u16* __restrict__ A, const u16* __restrict__ Bm,
    const float* __restrict__ b0, const float* __restrict__ b1, const float* __restrict__ b2,
    void* __restrict__ Cout, int K) {
    __shared__ __align__(16) u16 Ash[6 * 8192];   // 6 x (256 rows x 32 k) = 96 KB
    __shared__ __align__(16) u16 Bsh[6 * 4096];   // 6 x (128 rows x 32 k) = 48 KB

    const int tid = threadIdx.x;
    const int lane = tid & 63, wid = tid >> 6;
    const int wm = wid >> 1, wn = wid & 1;        // 4M x 2N wave grid
    const int m0 = blockIdx.x * 256, n0 = blockIdx.y * 128;
    const int r = lane & 15, g = lane >> 4;

    f32x4 acc[4][4] = {};

    const int p0 = tid >> 3;
    const int ci = tid & 7;
    const int cl = ci ^ (p0 & 7);
    const int trow = 2 * p0 + (cl >> 2);
    const int colb = (cl & 3) * 8;
    const u16* aS = A + (long)(m0 + trow) * K + colb;
    const u16* bS = Bm + (long)(n0 + trow) * K + colb;
    const long rowskip = (long)128 * K;
    const int ldst = tid * 8;

    auto STAGE = [&](int sig, int kq) {
        const u16* spA = aS + kq * 32;
        gload16(spA, &Ash[sig * 8192 + ldst]);
        gload16(spA + rowskip, &Ash[sig * 8192 + 4096 + ldst]);
        gload16(bS + kq * 32, &Bsh[sig * 4096 + ldst]);
    };

    const int xa = (((((r & 1) << 2) | g) ^ (r >> 1)) << 4);
    const int arow0 = wm * 32 + (r >> 1);
    const int brow0 = wn * 32 + (r >> 1);
    auto RD = [&](const u16* base, int prow) -> bf16x8 {
        return *(const bf16x8*)((const char*)base + prow * 128 + xa);
    };

    bf16x8 fa0[4], fb0[4], fa1[4], fb1[4];

    auto READF = [&](int rho, bf16x8* fa, bf16x8* fb) {
#pragma unroll
        for (int m = 0; m < 4; ++m) fa[m] = RD(&Ash[rho * 8192], arow0 + m * 8);
#pragma unroll
        for (int n = 0; n < 4; ++n) fb[n] = RD(&Bsh[rho * 4096], brow0 + n * 8);
    };
    auto MM = [&](bf16x8* fa, bf16x8* fb) {
        __builtin_amdgcn_s_setprio(1);
#pragma unroll
        for (int m = 0; m < 4; ++m)
#pragma unroll
            for (int n = 0; n < 4; ++n)
                acc[m][n] = __builtin_amdgcn_mfma_f32_16x16x32_bf16(fa[m], fb[n], acc[m][n], 0, 0, 0);
        __builtin_amdgcn_s_setprio(0);
    };
    auto BAR = [&] {
        asm volatile("" ::: "memory");
        __builtin_amdgcn_s_barrier();
        asm volatile("" ::: "memory");
    };

    const int nph = K >> 5;

    STAGE(0, 0); STAGE(1, 1); STAGE(2, 2); STAGE(3, 3); STAGE(4, 4);
    asm volatile("s_waitcnt vmcnt(9)" ::: "memory");
    BAR();
    READF(0, fa0, fb0);

    int rho = 0;
    for (int p = 0; p + 2 < nph; p += 2) {
        const int rho1 = rho + 1;
        const int rho2 = (rho + 2 == 6) ? 0 : rho + 2;
        const int sigE = (rho == 0) ? 5 : rho - 1;
        const int kqE = (p + 5 < nph) ? p + 5 : 0;
        const int kqO = (p + 6 < nph) ? p + 6 : 0;
        BAR();
        READF(rho1, fa1, fb1);
        STAGE(sigE, kqE);
        MM(fa0, fb0);
        asm volatile("s_waitcnt vmcnt(9)" ::: "memory");
        BAR();
        READF(rho2, fa0, fb0);
        STAGE(rho, kqO);
        MM(fa1, fb1);
        asm volatile("s_waitcnt vmcnt(9)" ::: "memory");
        rho = rho2;
    }
    {
        const int rho1 = rho + 1;
        const int sigE = (rho == 0) ? 5 : rho - 1;
        BAR();
        READF(rho1, fa1, fb1);
        STAGE(sigE, 0);
        MM(fa0, fb0);
        asm volatile("s_waitcnt vmcnt(9)" ::: "memory");
    }
    MM(fa1, fb1);
    asm volatile("s_waitcnt vmcnt(0)" ::: "memory");

    const long planeSz = (long)BZ * NH * TZ * HD;
    if constexpr (EPI == 0) {
        const int proj = n0 >> 10;
        u16* outp = (u16*)Cout;
        if (proj == 2) {
            const int bi = (m0 + wm * 64) >> 11;
#pragma unroll
            for (int n = 0; n < 4; ++n) {
                const int rr = (n0 & 1023) + wn * 64 + n * 16 + r;
                const int h = rr >> 6, d = rr & 63;
                const float bias = b2[rr];
                u16* vcol = outp + 2 * planeSz + (((long)bi * NH + h) * HD + d) * TZ;
#pragma unroll
                for (int m = 0; m < 4; ++m) {
                    const int t0 = (m0 + wm * 64 + m * 16 + g * 4) & 2047;
                    ushort4 o;
                    o.x = f2bf(acc[m][n][0] + bias);
                    o.y = f2bf(acc[m][n][1] + bias);
                    o.z = f2bf(acc[m][n][2] + bias);
                    o.w = f2bf(acc[m][n][3] + bias);
                    *(ushort4*)(vcol + t0) = o;
                }
            }
        } else {
#pragma unroll
            for (int n = 0; n < 4; ++n) {
                const int rr = (n0 & 1023) + wn * 64 + n * 16 + r;
                const int h = rr >> 6, d = rr & 63;
                float bias = (proj == 0 ? b0 : b1)[rr];
                if (proj == 0) bias *= QSCALE;
                const long pbase = (long)proj * planeSz + d;
#pragma unroll
                for (int m = 0; m < 4; ++m)
#pragma unroll
                    for (int reg = 0; reg < 4; ++reg) {
                        const int row = m0 + wm * 64 + m * 16 + g * 4 + reg;
                        const int bi = row >> 11, t = row & 2047;
                        outp[pbase + ((long)bi * NH + h) * (TZ * HD) + (long)t * HD] =
                            f2bf(acc[m][n][reg] + bias);
                    }
            }
        }
    } else {
        float* outp = (float*)Cout;
#pragma unroll
        for (int n = 0; n < 4; ++n) {
            const int col = n0 + wn * 64 + n * 16 + r;
            const float bias = b0[col];
#pragma unroll
            for (int m = 0; m < 4; ++m)
#pragma unroll
                for (int reg = 0; reg < 4; ++reg) {
                    const int row = m0 + wm * 64 + m * 16 + g * 4 + reg;
                    outp[(long)row * N_EMBD + col] = acc[m][n][reg] + bias;
                }
        }
    }
}

// ---------------- flash attention (causal, swapped-operand, in-register P) ----
// Round-4 verified structure: 512 blocks, 512 threads = 8 waves; wave owns 16
// q-rows; KVBLK=64; balanced pair of 128-row q-blocks (15-pr, pr) -> 36 tiles;
// 2 blocks/CU; 0 bank conflicts; last TWO tiles masked.
// NEW vs r4: V fragments are read IMMEDIATELY after the barrier (V resident
// same as K), so their LDS latency drains under QK^T + softmax instead of
// sitting on the softmax->PV critical path. +32 VGPR live (~100 total < 128).
__device__ __forceinline__ bf16x8 lds_swz8(const u16* base, int row, int colByte) {
    return *(const bf16x8*)((const char*)base + row * 128 + (colByte ^ ((row & 7) << 4)));
}

__global__ __launch_bounds__(512, 2) void attn_fwd(const u16* __restrict__ qkv, u16* __restrict__ yb) {
    const int i = blockIdx.x;
    const int xcd = i & 7, slot = i >> 3;
    const int bh = xcd + 8 * (slot & 7);     // 0..63, same-bh blocks share an XCD
    const int pr = slot >> 3;                // 0..7 pair id
    const int b = bh >> 4, h = bh & 15;
    const int tid = threadIdx.x, lane = tid & 63, w = tid >> 6;   // w 0..7
    const int r = lane & 15, g = lane >> 4;

    __shared__ __align__(16) u16 Ksh[2][64 * 64];   // [k][d] swizzled
    __shared__ __align__(16) u16 Vsh[2][64 * 64];   // [d][k] swizzled

    const long planeSz = (long)BZ * NH * TZ * HD;
    const long bhoff = ((long)b * NH + h) * (long)TZ * HD;
    const u16* qp = qkv + bhoff;
    const u16* kp = qkv + planeSz + bhoff;
    const u16* vTp = qkv + 2 * planeSz + bhoff;      // [64][T]

    // staging coords: 512 threads cover a full 64x64 bf16 tile in ONE gload
    const int rr8 = tid >> 3;                 // tile row 0..63
    const int ss = ((tid & 7) ^ (rr8 & 7)) * 8;   // pre-swizzled source chunk

#pragma unroll 1
    for (int it = 0; it < 2; ++it) {
        const int qblk = it ? pr : (15 - pr);
        const int q0 = qblk * 128;
        const int nkt = 2 * qblk + 2;

        // hoist Q fragments (B-operand: lane r = q-col, g*8 = d-chunk)
        bf16x8 qf[2];
        {
            const int q = q0 + w * 16 + r;
#pragma unroll
            for (int ks = 0; ks < 2; ++ks)
                qf[ks] = *(const bf16x8*)(qp + (long)q * HD + ks * 32 + g * 8);
        }

        f32x4 yacc[4] = {};                    // y^T: [d-frag][q=r]
        float mrun = -__builtin_inff(), lpart = 0.f;

        // prologue stage tile 0 (K: 8KB, V: 8KB -> 2 gloads)
        gload16(kp + (long)rr8 * HD + ss, &Ksh[0][tid * 8]);
        gload16(vTp + (long)rr8 * TZ + ss, &Vsh[0][tid * 8]);

        auto tile = [&](int kt, auto maskc) {
            constexpr bool MASK = decltype(maskc)::value;
            const int cur = kt & 1;
            const int k0 = kt * 64;
            if (kt + 1 < nkt) {
                const int k0n = k0 + 64;
                gload16(kp + (long)(k0n + rr8) * HD + ss, &Ksh[cur ^ 1][tid * 8]);
                gload16(vTp + (long)rr8 * TZ + k0n + ss, &Vsh[cur ^ 1][tid * 8]);
                asm volatile("s_waitcnt vmcnt(2)" ::: "memory");
            } else {
                asm volatile("s_waitcnt vmcnt(0)" ::: "memory");
            }
            __builtin_amdgcn_s_barrier();
            asm volatile("" ::: "memory");

            // EARLY V fragment reads: oldest in lgkm queue, drain under QK+softmax
            bf16x8 vf[2][4];
#pragma unroll
            for (int ks = 0; ks < 2; ++ks)
#pragma unroll
                for (int nd = 0; nd < 4; ++nd)
                    vf[ks][nd] = lds_swz8(Vsh[cur], nd * 16 + r, ks * 64 + g * 16);

            // S^T = K · Q^T  -> sac[nk]: row k, col q
            f32x4 sac[4] = {};
#pragma unroll
            for (int ks = 0; ks < 2; ++ks) {
                bf16x8 kf[4];
#pragma unroll
                for (int nk = 0; nk < 4; ++nk)
                    kf[nk] = lds_swz8(Ksh[cur], nk * 16 + r, ks * 64 + g * 16);
                __builtin_amdgcn_s_setprio(1);
#pragma unroll
                for (int nk = 0; nk < 4; ++nk)
                    sac[nk] = __builtin_amdgcn_mfma_f32_16x16x32_bf16(kf[nk], qf[ks], sac[nk], 0, 0, 0);
                __builtin_amdgcn_s_setprio(0);
            }

            // online softmax (log2 domain). lane owns 16 k of q-row r.
            if constexpr (MASK) {
                const int q = q0 + w * 16 + r;
#pragma unroll
                for (int nk = 0; nk < 4; ++nk)
#pragma unroll
                    for (int reg = 0; reg < 4; ++reg) {
                        const int k = k0 + nk * 16 + g * 4 + reg;
                        sac[nk][reg] = (k > q) ? -__builtin_inff() : sac[nk][reg];
                    }
            }
            float pmax;
            {
                float t0 = fmaxf(fmaxf(sac[0][0], sac[0][1]), fmaxf(sac[0][2], sac[0][3]));
                float t1 = fmaxf(fmaxf(sac[1][0], sac[1][1]), fmaxf(sac[1][2], sac[1][3]));
                float t2 = fmaxf(fmaxf(sac[2][0], sac[2][1]), fmaxf(sac[2][2], sac[2][3]));
                float t3 = fmaxf(fmaxf(sac[3][0], sac[3][1]), fmaxf(sac[3][2], sac[3][3]));
                pmax = fmaxf(fmaxf(t0, t1), fmaxf(t2, t3));
            }
            if (__any(pmax > mrun + 8.0f)) {
                float mx = pmax;
                mx = fmaxf(mx, __shfl_xor(mx, 16));
                mx = fmaxf(mx, __shfl_xor(mx, 32));
                const float mnew = fmaxf(mrun, mx);
                const float corr = __builtin_amdgcn_exp2f(mrun - mnew);
                lpart *= corr;
#pragma unroll
                for (int nd = 0; nd < 4; ++nd)
                    yacc[nd] *= corr;
                mrun = mnew;
            }
            float rs[4];
#pragma unroll
            for (int nk = 0; nk < 4; ++nk) {
                float p0 = __builtin_amdgcn_exp2f(sac[nk][0] - mrun);
                float p1 = __builtin_amdgcn_exp2f(sac[nk][1] - mrun);
                float p2 = __builtin_amdgcn_exp2f(sac[nk][2] - mrun);
                float p3 = __builtin_amdgcn_exp2f(sac[nk][3] - mrun);
                sac[nk][0] = p0; sac[nk][1] = p1;
                sac[nk][2] = p2; sac[nk][3] = p3;
                rs[nk] = (p0 + p1) + (p2 + p3);
            }
            lpart += (rs[0] + rs[1]) + (rs[2] + rs[3]);

            // pack P to bf16 + permlane exchange -> PV B-operand in-register
            u32 wv[4][2];
#pragma unroll
            for (int nk = 0; nk < 4; ++nk)
#pragma unroll
                for (int j2 = 0; j2 < 2; ++j2)
                    asm("v_cvt_pk_bf16_f32 %0, %1, %2"
                        : "=v"(wv[nk][j2])
                        : "v"(sac[nk][2 * j2]), "v"(sac[nk][2 * j2 + 1]));
            u32 pw[2][4];
#pragma unroll
            for (int ks = 0; ks < 2; ++ks) {
                u32 a0 = wv[2 * ks][0], b0 = wv[2 * ks + 1][0];
                u32 a1 = wv[2 * ks][1], b1 = wv[2 * ks + 1][1];
                asm("v_permlane32_swap_b32 %0, %1" : "+v"(a0), "+v"(b0));
                asm("v_permlane32_swap_b32 %0, %1" : "+v"(a1), "+v"(b1));
                asm("v_permlane16_swap_b32 %0, %1" : "+v"(a0), "+v"(b0));
                asm("v_permlane16_swap_b32 %0, %1" : "+v"(a1), "+v"(b1));
                pw[ks][0] = a0; pw[ks][1] = a1;
                pw[ks][2] = b0; pw[ks][3] = b1;
            }

            // y^T += V^T · P^T (vf pre-read)
#pragma unroll
            for (int ks = 0; ks < 2; ++ks) {
                const u32x4 pwv = { pw[ks][0], pw[ks][1], pw[ks][2], pw[ks][3] };
                const bf16x8 pb = __builtin_bit_cast(bf16x8, pwv);
                __builtin_amdgcn_s_setprio(1);
#pragma unroll
                for (int nd = 0; nd < 4; ++nd)
                    yacc[nd] = __builtin_amdgcn_mfma_f32_16x16x32_bf16(vf[ks][nd], pb, yacc[nd], 0, 0, 0);
                __builtin_amdgcn_s_setprio(0);
            }

            asm volatile("" ::: "memory");
            __builtin_amdgcn_s_barrier();
            asm volatile("" ::: "memory");
        };

        for (int kt = 0; kt + 2 < nkt; ++kt) tile(kt, BoolC<false>{});
        tile(nkt - 2, BoolC<true>{});     // 128-row q-block spans TWO diagonal tiles
        tile(nkt - 1, BoolC<true>{});

        // epilogue: reduce l across g-lanes, y = y^T / l
        {
            float l = lpart;
            l += __shfl_xor(l, 16);
            l += __shfl_xor(l, 32);
            const float inv = 1.f / l;
            const int q = q0 + w * 16 + r;
            u16* orow = yb + ((long)b * TZ + q) * N_EMBD + h * HD;
#pragma unroll
            for (int nd = 0; nd < 4; ++nd) {
                ushort4 o;
                o.x = f2bf(yacc[nd][0] * inv);
                o.y = f2bf(yacc[nd][1] * inv);
                o.z = f2bf(yacc[nd][2] * inv);
                o.w = f2bf(yacc[nd][3] * inv);
                *(ushort4*)(orow + nd * 16 + g * 4) = o;
            }
        }
    }
}

extern "C" void kernel_launch(void* const* d_in, const int* in_sizes, int n_in,
                              void* d_out, int out_size, void* d_ws, size_t ws_size,
                              hipStream_t stream) {
    const float* x  = (const float*)d_in[0];
    const float* Wq = (const float*)d_in[1];
    const float* bq = (const float*)d_in[2];
    const float* Wk = (const float*)d_in[3];
    const float* bk = (const float*)d_in[4];
    const float* Wv = (const float*)d_in[5];
    const float* bv = (const float*)d_in[6];
    const float* Wc = (const float*)d_in[7];
    const float* bc = (const float*)d_in[8];

    char* ws = (char*)d_ws;
    u16* xb   = (u16*)(ws);                  // 8192x1024 bf16   (16 MB)
    u16* wqkv = (u16*)(ws + 16777216);       // 3072x1024 bf16   (6 MB)
    u16* wcb  = (u16*)(ws + 23068672);       // 1024x1024 bf16   (2 MB)
    u16* qkv  = (u16*)(ws + 25165824);       // Q,K,[V^T] planes (48 MB)
    u16* yb   = (u16*)(ws + 75497472);       // 8192x1024 bf16   (16 MB)

    // fused converts (Wq pre-scaled by QSCALE so S arrives in log2 domain)
    cvt_all<<<12288, 256, 0, stream>>>(x, Wq, Wk, Wv, Wc, xb, wqkv, wcb);

    // qkv projection: [8192,1024] x [3072,1024]^T -> qkv scatter (V transposed)
    gemm_bt<0><<<dim3(32, 24), 512, 0, stream>>>(xb, wqkv, bq, bk, bv, (void*)qkv, 1024);

    // causal attention (128-row paired q-blocks, 8-wave blocks, KVBLK=64, early-V)
    attn_fwd<<<512, 512, 0, stream>>>(qkv, yb);

    // output projection: [8192,1024] x [1024,1024]^T + bc -> fp32 out
    gemm_bt<1><<<dim3(32, 8), 512, 0, stream>>>(yb, wcb, bc, nullptr, nullptr, d_out, 1024);
}